// Round 18
// baseline (196.439 us; speedup 1.0000x reference)
//
#include <hip/hip_runtime.h>
#include <hip/hip_bf16.h>

// B=32, S=2048, D=1024, C=256
//   top[b,s] = max_c sum_d (latent[c,d]*att_diag[d]) * (tm*embeds[b,s,d] + pos_table[rel+64,d])
//   p = softmax_s(top*m + (m-1)*NEG);  ctx[b,d] = tok_diag[d] * sum_s embeds*p
//
// R18 = R11 core + two mechanical fixes:
//  1) depth-2 e/p prefetch (A/B reg sets, loop unrolled x2) + correct
//     counted wait vmcnt(8): at each barrier the FIFO drains EP(kc+1)+
//     stage(kc+1) (both issued a full body earlier) and leaves EP(kc+2)
//     in flight. R11's vmcnt(4) was an over-wait that drained half the
//     e/p prefetch each kc.
//  2) k_finish parallelized: grid 32 -> 128 blocks (per-(b, d-quarter)).
// 2-term split-fp16 MFMA: W_hi*(x_hi+x_lo), x = tm*e + p (f32 merge).
// Flash epilogue per 128-token block (M_b, Z_b, P).
//
// ws: whi 512K | partial 2M | mblk 2K | zblk 2K

#define HC 64
#define NEGV 1000000000000.0f

constexpr int Bb = 32, Ss = 2048, Dd = 1024, Cc = 256;
constexpr int NKC = 32;                 // k-chunks of 32
constexpr int CT = Cc / 16;             // 16 c-tiles
constexpr int NBLK = 16;                // 128-token blocks per batch

typedef _Float16 f16x8 __attribute__((ext_vector_type(8)));
typedef float    f32x4 __attribute__((ext_vector_type(4)));

// ---------------- Pass 0: W_hi -> per-kc fragment chunks ----------
// layout: whi[kc][ct][lane][8] (16KB/kc)
// A-frag map: lane = (c%16) + 16*g holds A[c][k = kc*32 + 8g + i]
__global__ __launch_bounds__(256) void k_prep_w(
    const float* __restrict__ latent, const float* __restrict__ att_diag,
    _Float16* __restrict__ whi)
{
    const int idx = blockIdx.x * 256 + threadIdx.x;   // c*Dd + k
    const int c = idx >> 10, k = idx & 1023;
    const float wv = latent[idx] * att_diag[k];
    const int kc = k >> 5, g = (k >> 3) & 3, i = k & 7;
    const int lane = (c & 15) + 16 * g, ct = c >> 4;
    whi[(size_t)kc * 8192 + (size_t)ct * 512 + lane * 8 + i] = (_Float16)wv;
}

// ------- Pass 1: scores via MFMA, block max/sumexp, flash ctx partial -----
__global__ __launch_bounds__(256, 2) void k_scores_mfma(
    const float* __restrict__ embeds,    // [B][S][D]
    const float* __restrict__ mask,      // [B][S]
    const float* __restrict__ pos_table, // [132][D]
    const float* __restrict__ tok_mult,  // [1]
    const int*   __restrict__ rel_ids,   // [B][S]
    const _Float16* __restrict__ whi,    // [NKC][CT][64][8]
    float* __restrict__ partial,         // [B][NBLK][D]
    float* __restrict__ mblk,            // [B][NBLK]
    float* __restrict__ zblk)            // [B][NBLK]
{
    __shared__ _Float16 sbuf[2][8192];   // 2 x 16KB (W_hi chunks)
    __shared__ float l_sh[128];
    __shared__ float w_sh[128];
    __shared__ float red2[2], zred[2];

    const int t  = threadIdx.x;
    const int wv = t >> 6;      // wave 0..3
    const int l  = t & 63;
    const int lr = l & 15;      // token within set / output col
    const int lg = l >> 4;      // k-group

    const int b   = blockIdx.x >> 4;     // 16 blocks of 128 tokens per batch
    const int blk = blockIdx.x & 15;
    const int s0  = blk * 128;

    const float tm = tok_mult[0];

    const float* erow[2];
    const float* prow[2];
    #pragma unroll
    for (int st = 0; st < 2; st++) {
        const int tok = s0 + wv * 32 + st * 16 + lr;
        erow[st] = embeds + ((size_t)b * Ss + tok) * Dd;
        prow[st] = pos_table + (size_t)(rel_ids[b * Ss + tok] + HC) * Dd;
    }

    f32x4 acc[CT][2];
    #pragma unroll
    for (int ct = 0; ct < CT; ct++)
        #pragma unroll
        for (int st = 0; st < 2; st++) acc[ct][st] = (f32x4){0.f, 0.f, 0.f, 0.f};

    // depth-2 e/p prefetch: two register sets (A = even kc, B = odd kc)
    f32x4 eA0[2], eA1[2], pA0[2], pA1[2];
    f32x4 eB0[2], eB1[2], pB0[2], pB1[2];
    auto loadEPA = [&](int kc) {   // 8 loads
        const int k0 = kc * 32 + lg * 8;
        #pragma unroll
        for (int st = 0; st < 2; st++) {
            eA0[st] = *(const f32x4*)(erow[st] + k0);
            eA1[st] = *(const f32x4*)(erow[st] + k0 + 4);
            pA0[st] = *(const f32x4*)(prow[st] + k0);
            pA1[st] = *(const f32x4*)(prow[st] + k0 + 4);
        }
    };
    auto loadEPB = [&](int kc) {   // 8 loads
        const int k0 = kc * 32 + lg * 8;
        #pragma unroll
        for (int st = 0; st < 2; st++) {
            eB0[st] = *(const f32x4*)(erow[st] + k0);
            eB1[st] = *(const f32x4*)(erow[st] + k0 + 4);
            pB0[st] = *(const f32x4*)(prow[st] + k0);
            pB1[st] = *(const f32x4*)(prow[st] + k0 + 4);
        }
    };

    // stage one 16KB W_hi chunk: 16 wave-chunks of 1KB (4 per wave)
    auto stage = [&](int kc, _Float16* dst) {
        const _Float16* src = whi + (size_t)kc * 8192;
        #pragma unroll
        for (int i = 0; i < 4; i++) {
            const int off = (i * 4 + wv) << 9;   // elems; 1KB chunks
            __builtin_amdgcn_global_load_lds(
                (const __attribute__((address_space(1))) void*)(src + off + l * 8),
                (__attribute__((address_space(3))) void*)(dst + off),
                16, 0, 0);
        }
    };

    // build hi/lo B-frags from one set's regs, then 64 MFMA on sbuf chunk
    auto body = [&](const f32x4* E0, const f32x4* E1, const f32x4* P0,
                    const f32x4* P1, const _Float16* base) {
        f16x8 bh[2], bl[2];
        #pragma unroll
        for (int st = 0; st < 2; st++) {
            float e[8], p[8];
            *(f32x4*)&e[0] = E0[st]; *(f32x4*)&e[4] = E1[st];
            *(f32x4*)&p[0] = P0[st]; *(f32x4*)&p[4] = P1[st];
            #pragma unroll
            for (int i = 0; i < 8; i++) {
                const float x = fmaf(tm, e[i], p[i]);
                const _Float16 h = (_Float16)x;
                bh[st][i] = h;
                bl[st][i] = (_Float16)(x - (float)h);
            }
        }
        #pragma unroll
        for (int ct = 0; ct < CT; ct++) {
            const f16x8 ah = *(const f16x8*)(base + ct * 512 + l * 8);
            #pragma unroll
            for (int st = 0; st < 2; st++) {
                acc[ct][st] = __builtin_amdgcn_mfma_f32_16x16x32_f16(ah, bh[st], acc[ct][st], 0, 0, 0);
                acc[ct][st] = __builtin_amdgcn_mfma_f32_16x16x32_f16(ah, bl[st], acc[ct][st], 0, 0, 0);
            }
        }
    };

    // prologue: stage(0) (oldest), EP(0), EP(1)
    stage(0, sbuf[0]);
    loadEPA(0);
    loadEPB(1);
    asm volatile("s_waitcnt vmcnt(8)" ::: "memory");  // stage(0)+EPA(0) landed
    __builtin_amdgcn_s_barrier();

    int cur = 0;
    for (int kc = 0; kc < NKC; kc += 2) {
        // ---- body A (kc): consumes EPA(kc) ----
        if (kc + 1 < NKC) stage(kc + 1, sbuf[cur ^ 1]);
        {
            f16x8 dummy; (void)dummy;
        }
        // build must read EPA before loadEPA overwrites it: body() reads first
        // but the prefetch must be issued before MFMA for overlap -> split:
        {
            // build frags now (consumes EPA regs)
            f16x8 bh[2], bl[2];
            #pragma unroll
            for (int st = 0; st < 2; st++) {
                float e[8], p[8];
                *(f32x4*)&e[0] = eA0[st]; *(f32x4*)&e[4] = eA1[st];
                *(f32x4*)&p[0] = pA0[st]; *(f32x4*)&p[4] = pA1[st];
                #pragma unroll
                for (int i = 0; i < 8; i++) {
                    const float x = fmaf(tm, e[i], p[i]);
                    const _Float16 h = (_Float16)x;
                    bh[st][i] = h;
                    bl[st][i] = (_Float16)(x - (float)h);
                }
            }
            if (kc + 2 < NKC) loadEPA(kc + 2);   // 8 loads, 2 bodies ahead
            const _Float16* base = sbuf[cur];
            #pragma unroll
            for (int ct = 0; ct < CT; ct++) {
                const f16x8 ah = *(const f16x8*)(base + ct * 512 + l * 8);
                #pragma unroll
                for (int st = 0; st < 2; st++) {
                    acc[ct][st] = __builtin_amdgcn_mfma_f32_16x16x32_f16(ah, bh[st], acc[ct][st], 0, 0, 0);
                    acc[ct][st] = __builtin_amdgcn_mfma_f32_16x16x32_f16(ah, bl[st], acc[ct][st], 0, 0, 0);
                }
            }
        }
        if (kc + 2 < NKC) { asm volatile("s_waitcnt vmcnt(8)" ::: "memory"); }
        else              { asm volatile("s_waitcnt vmcnt(0)" ::: "memory"); }
        __builtin_amdgcn_s_barrier();
        cur ^= 1;

        // ---- body B (kc+1): consumes EPB(kc+1) ----
        if (kc + 2 < NKC) stage(kc + 2, sbuf[cur ^ 1]);
        {
            f16x8 bh[2], bl[2];
            #pragma unroll
            for (int st = 0; st < 2; st++) {
                float e[8], p[8];
                *(f32x4*)&e[0] = eB0[st]; *(f32x4*)&e[4] = eB1[st];
                *(f32x4*)&p[0] = pB0[st]; *(f32x4*)&p[4] = pB1[st];
                #pragma unroll
                for (int i = 0; i < 8; i++) {
                    const float x = fmaf(tm, e[i], p[i]);
                    const _Float16 h = (_Float16)x;
                    bh[st][i] = h;
                    bl[st][i] = (_Float16)(x - (float)h);
                }
            }
            if (kc + 3 < NKC) loadEPB(kc + 3);   // 8 loads, 2 bodies ahead
            const _Float16* base = sbuf[cur];
            #pragma unroll
            for (int ct = 0; ct < CT; ct++) {
                const f16x8 ah = *(const f16x8*)(base + ct * 512 + l * 8);
                #pragma unroll
                for (int st = 0; st < 2; st++) {
                    acc[ct][st] = __builtin_amdgcn_mfma_f32_16x16x32_f16(ah, bh[st], acc[ct][st], 0, 0, 0);
                    acc[ct][st] = __builtin_amdgcn_mfma_f32_16x16x32_f16(ah, bl[st], acc[ct][st], 0, 0, 0);
                }
            }
        }
        if (kc + 3 < NKC) { asm volatile("s_waitcnt vmcnt(8)" ::: "memory"); }
        else              { asm volatile("s_waitcnt vmcnt(0)" ::: "memory"); }
        __builtin_amdgcn_s_barrier();
        cur ^= 1;
    }

    // masked logit per token -> LDS
    #pragma unroll
    for (int st = 0; st < 2; st++) {
        float mx = acc[0][st][0];
        #pragma unroll
        for (int ct = 0; ct < CT; ct++)
            #pragma unroll
            for (int r = 0; r < 4; r++) mx = fmaxf(mx, acc[ct][st][r]);
        mx = fmaxf(mx, __shfl_xor(mx, 16));
        mx = fmaxf(mx, __shfl_xor(mx, 32));
        if (lg == 0) {
            const int si = wv * 32 + st * 16 + lr;   // token within block
            const int s  = s0 + si;
            const float mk = mask[b * Ss + s];
            l_sh[si] = mx * mk + (mk - 1.0f) * NEGV;
        }
    }
    __syncthreads();

    // block max M_b over the 128 logits
    if (t < 128) {
        float v = l_sh[t];
        #pragma unroll
        for (int o = 32; o >= 1; o >>= 1) v = fmaxf(v, __shfl_xor(v, o));
        if ((t & 63) == 0) red2[t >> 6] = v;
    }
    __syncthreads();
    const float Mb = fmaxf(red2[0], red2[1]);
    if (t < 128) w_sh[t] = expf(l_sh[t] - Mb);
    __syncthreads();
    if (t < 128) {
        float z = w_sh[t];
        #pragma unroll
        for (int o = 32; o >= 1; o >>= 1) z += __shfl_xor(z, o);
        if ((t & 63) == 0) zred[t >> 6] = z;
    }
    __syncthreads();

    // block-local ctx partial: P[d] = sum_s w_sh[s] * e[s0+s][d]  (L2-hot)
    {
        const float* eb = embeds + ((size_t)b * Ss + s0) * Dd + t * 4;
        f32x4 ca = (f32x4){0.f, 0.f, 0.f, 0.f};
        #pragma unroll 8
        for (int s = 0; s < 128; s++) {
            const float wgt = w_sh[s];
            const f32x4 ev = *(const f32x4*)(eb + (size_t)s * Dd);
            ca[0] = fmaf(wgt, ev[0], ca[0]);
            ca[1] = fmaf(wgt, ev[1], ca[1]);
            ca[2] = fmaf(wgt, ev[2], ca[2]);
            ca[3] = fmaf(wgt, ev[3], ca[3]);
        }
        *(f32x4*)(partial + ((size_t)(b * NBLK + blk)) * Dd + t * 4) = ca;
        if (t == 0) {
            mblk[b * NBLK + blk] = Mb;
            zblk[b * NBLK + blk] = zred[0] + zred[1];
        }
    }
}

// ------- Pass 2: global flash combine + tok_diag (parallel over d) -------
__global__ __launch_bounds__(256) void k_finish(
    const float* __restrict__ mblk, const float* __restrict__ zblk,
    const float* __restrict__ partial, const float* __restrict__ tok_diag,
    float* __restrict__ out)
{
    __shared__ float cf[NBLK];
    const int b  = blockIdx.x >> 2;      // batch
    const int dq = blockIdx.x & 3;       // d quarter (256 floats)
    const int t  = threadIdx.x;

    if (t < 64) {
        const float mv = (t < NBLK) ? mblk[b * NBLK + t] : -3.4e38f;
        float M = mv;
        #pragma unroll
        for (int o = 32; o >= 1; o >>= 1) M = fmaxf(M, __shfl_xor(M, o));
        const float zv = (t < NBLK) ? zblk[b * NBLK + t] * expf(mv - M) : 0.f;
        float Z = zv;
        #pragma unroll
        for (int o = 32; o >= 1; o >>= 1) Z += __shfl_xor(Z, o);
        if (t < NBLK) cf[t] = expf(mv - M) / Z;
    }
    __syncthreads();

    const int d = dq * 256 + t;          // one float per thread, coalesced
    float a = 0.f;
    #pragma unroll
    for (int j = 0; j < NBLK; j++)
        a = fmaf(cf[j], partial[((size_t)(b * NBLK + j)) * Dd + d], a);
    out[(size_t)b * Dd + d] = a * tok_diag[d];
}

extern "C" void kernel_launch(void* const* d_in, const int* in_sizes, int n_in,
                              void* d_out, int out_size, void* d_ws, size_t ws_size,
                              hipStream_t stream) {
    const float* embeds    = (const float*)d_in[0];
    const float* mask      = (const float*)d_in[1];
    const float* latent    = (const float*)d_in[2];
    const float* att_diag  = (const float*)d_in[3];
    const float* tok_diag  = (const float*)d_in[4];
    const float* pos_table = (const float*)d_in[5];
    const float* tok_mult  = (const float*)d_in[6];
    const int*   rel_ids   = (const int*)d_in[7];
    float* out = (float*)d_out;

    char* ws = (char*)d_ws;
    _Float16* whi    = (_Float16*)(ws);              // 512 KB
    float*    partial= (float*)(ws + 524288);        // 2 MB
    float*    mblk   = (float*)(ws + 2621440);       // 2 KB
    float*    zblk   = (float*)(ws + 2623488);       // 2 KB

    k_prep_w<<<(Cc * Dd) / 256, 256, 0, stream>>>(latent, att_diag, whi);
    k_scores_mfma<<<Bb * NBLK, 256, 0, stream>>>(
        embeds, mask, pos_table, tok_mult, rel_ids, whi, partial, mblk, zblk);
    k_finish<<<Bb * 4, 256, 0, stream>>>(mblk, zblk, partial, tok_diag, out);
}

// Round 19
// 121.356 us; speedup vs baseline: 1.6187x; 1.6187x over previous
//
#include <hip/hip_runtime.h>
#include <hip/hip_bf16.h>

// B=32, S=2048, D=1024, C=256
//   top[b,s] = max_c sum_d (latent[c,d]*att_diag[d]) * (tm*embeds[b,s,d] + pos_table[rel+64,d])
//   p = softmax_s(top*m + (m-1)*NEG);  ctx[b,d] = tok_diag[d] * sum_s embeds*p
//
// R19 = R11 (best, 121.9us) + two verified-safe deltas:
//  1) k_finish parallelized 32 -> 128 blocks (verified correct in R18 run).
//  2) in-loop counted wait vmcnt(4) -> vmcnt(8): drains exactly the 4 stage
//     loads (FIFO: stage issued before loadEP), keeps all 8 e/p prefetches
//     in flight across the barrier (R11 over-waited, draining half of them).
//     Final iteration drains to 0.
// Core: 2-term split-fp16 MFMA (W_hi*(x_hi+x_lo), x = tm*e + p), 4 waves /
// 128 tokens / dbuf 16KB W staging via global_load_lds; flash epilogue with
// per-block (M_b, Z_b, P); k_finish combines.
//
// ws: whi 512K | partial 2M | mblk 2K | zblk 2K

#define HC 64
#define NEGV 1000000000000.0f

constexpr int Bb = 32, Ss = 2048, Dd = 1024, Cc = 256;
constexpr int NKC = 32;                 // k-chunks of 32
constexpr int CT = Cc / 16;             // 16 c-tiles
constexpr int NBLK = 16;                // 128-token blocks per batch

typedef _Float16 f16x8 __attribute__((ext_vector_type(8)));
typedef float    f32x4 __attribute__((ext_vector_type(4)));

// ---------------- Pass 0: W_hi -> per-kc fragment chunks ----------
// layout: whi[kc][ct][lane][8] (16KB/kc)
// A-frag map: lane = (c%16) + 16*g holds A[c][k = kc*32 + 8g + i]
__global__ __launch_bounds__(256) void k_prep_w(
    const float* __restrict__ latent, const float* __restrict__ att_diag,
    _Float16* __restrict__ whi)
{
    const int idx = blockIdx.x * 256 + threadIdx.x;   // c*Dd + k
    const int c = idx >> 10, k = idx & 1023;
    const float wv = latent[idx] * att_diag[k];
    const int kc = k >> 5, g = (k >> 3) & 3, i = k & 7;
    const int lane = (c & 15) + 16 * g, ct = c >> 4;
    whi[(size_t)kc * 8192 + (size_t)ct * 512 + lane * 8 + i] = (_Float16)wv;
}

// ------- Pass 1: scores via MFMA, block max/sumexp, flash ctx partial -----
__global__ __launch_bounds__(256, 2) void k_scores_mfma(
    const float* __restrict__ embeds,    // [B][S][D]
    const float* __restrict__ mask,      // [B][S]
    const float* __restrict__ pos_table, // [132][D]
    const float* __restrict__ tok_mult,  // [1]
    const int*   __restrict__ rel_ids,   // [B][S]
    const _Float16* __restrict__ whi,    // [NKC][CT][64][8]
    float* __restrict__ partial,         // [B][NBLK][D]
    float* __restrict__ mblk,            // [B][NBLK]
    float* __restrict__ zblk)            // [B][NBLK]
{
    __shared__ _Float16 sbuf[2][8192];   // 2 x 16KB (W_hi chunks)
    __shared__ float l_sh[128];
    __shared__ float w_sh[128];
    __shared__ float red2[2], zred[2];

    const int t  = threadIdx.x;
    const int wv = t >> 6;      // wave 0..3
    const int l  = t & 63;
    const int lr = l & 15;      // token within set / output col
    const int lg = l >> 4;      // k-group

    const int b   = blockIdx.x >> 4;     // 16 blocks of 128 tokens per batch
    const int blk = blockIdx.x & 15;
    const int s0  = blk * 128;

    const float tm = tok_mult[0];

    const float* erow[2];
    const float* prow[2];
    #pragma unroll
    for (int st = 0; st < 2; st++) {
        const int tok = s0 + wv * 32 + st * 16 + lr;
        erow[st] = embeds + ((size_t)b * Ss + tok) * Dd;
        prow[st] = pos_table + (size_t)(rel_ids[b * Ss + tok] + HC) * Dd;
    }

    f32x4 acc[CT][2];
    #pragma unroll
    for (int ct = 0; ct < CT; ct++)
        #pragma unroll
        for (int st = 0; st < 2; st++) acc[ct][st] = (f32x4){0.f, 0.f, 0.f, 0.f};

    // e/p prefetch registers (one kc ahead): 8 global loads per call
    f32x4 e0[2], e1[2], p0[2], p1[2];
    auto loadEP = [&](int kc) {
        const int k0 = kc * 32 + lg * 8;
        #pragma unroll
        for (int st = 0; st < 2; st++) {
            e0[st] = *(const f32x4*)(erow[st] + k0);
            e1[st] = *(const f32x4*)(erow[st] + k0 + 4);
            p0[st] = *(const f32x4*)(prow[st] + k0);
            p1[st] = *(const f32x4*)(prow[st] + k0 + 4);
        }
    };

    // stage one 16KB W_hi chunk: 16 wave-chunks of 1KB (4 per wave)
    auto stage = [&](int kc, _Float16* dst) {
        const _Float16* src = whi + (size_t)kc * 8192;
        #pragma unroll
        for (int i = 0; i < 4; i++) {
            const int off = (i * 4 + wv) << 9;   // elems; 1KB chunks
            __builtin_amdgcn_global_load_lds(
                (const __attribute__((address_space(1))) void*)(src + off + l * 8),
                (__attribute__((address_space(3))) void*)(dst + off),
                16, 0, 0);
        }
    };

    // prologue: stage first (oldest), then e/p
    stage(0, sbuf[0]);
    loadEP(0);
    asm volatile("s_waitcnt vmcnt(8)" ::: "memory");  // stage(0) done (e/p may fly)
    __builtin_amdgcn_s_barrier();

    int cur = 0;
    for (int kc = 0; kc < NKC; kc++) {
        if (kc + 1 < NKC) stage(kc + 1, sbuf[cur ^ 1]);   // oldest VMEM this iter

        // build current B frags (e split hi/lo fp16); consumes e/p(kc) regs
        f16x8 bh[2], bl[2];
        #pragma unroll
        for (int st = 0; st < 2; st++) {
            float e[8], p[8];
            *(f32x4*)&e[0] = e0[st]; *(f32x4*)&e[4] = e1[st];
            *(f32x4*)&p[0] = p0[st]; *(f32x4*)&p[4] = p1[st];
            #pragma unroll
            for (int i = 0; i < 8; i++) {
                const float x = fmaf(tm, e[i], p[i]);
                const _Float16 h = (_Float16)x;
                bh[st][i] = h;
                bl[st][i] = (_Float16)(x - (float)h);
            }
        }
        if (kc + 1 < NKC) loadEP(kc + 1);   // 8 HBM loads; stay in flight past barrier

        const _Float16* base = sbuf[cur];
        #pragma unroll
        for (int ct = 0; ct < CT; ct++) {
            const f16x8 ah = *(const f16x8*)(base + ct * 512 + l * 8);
            #pragma unroll
            for (int st = 0; st < 2; st++) {
                acc[ct][st] = __builtin_amdgcn_mfma_f32_16x16x32_f16(ah, bh[st], acc[ct][st], 0, 0, 0);
                acc[ct][st] = __builtin_amdgcn_mfma_f32_16x16x32_f16(ah, bl[st], acc[ct][st], 0, 0, 0);
            }
        }
        // counted wait: drain exactly the 4 stage loads (issued before loadEP);
        // all 8 e/p prefetch loads stay in flight across the barrier.
        if (kc + 1 < NKC) { asm volatile("s_waitcnt vmcnt(8)" ::: "memory"); }
        else              { asm volatile("s_waitcnt vmcnt(0)" ::: "memory"); }
        __builtin_amdgcn_s_barrier();
        cur ^= 1;
    }

    // masked logit per token -> LDS
    #pragma unroll
    for (int st = 0; st < 2; st++) {
        float mx = acc[0][st][0];
        #pragma unroll
        for (int ct = 0; ct < CT; ct++)
            #pragma unroll
            for (int r = 0; r < 4; r++) mx = fmaxf(mx, acc[ct][st][r]);
        mx = fmaxf(mx, __shfl_xor(mx, 16));
        mx = fmaxf(mx, __shfl_xor(mx, 32));
        if (lg == 0) {
            const int si = wv * 32 + st * 16 + lr;   // token within block
            const int s  = s0 + si;
            const float mk = mask[b * Ss + s];
            l_sh[si] = mx * mk + (mk - 1.0f) * NEGV;
        }
    }
    __syncthreads();

    // block max M_b over the 128 logits
    if (t < 128) {
        float v = l_sh[t];
        #pragma unroll
        for (int o = 32; o >= 1; o >>= 1) v = fmaxf(v, __shfl_xor(v, o));
        if ((t & 63) == 0) red2[t >> 6] = v;
    }
    __syncthreads();
    const float Mb = fmaxf(red2[0], red2[1]);
    if (t < 128) w_sh[t] = expf(l_sh[t] - Mb);
    __syncthreads();
    if (t < 128) {
        float z = w_sh[t];
        #pragma unroll
        for (int o = 32; o >= 1; o >>= 1) z += __shfl_xor(z, o);
        if ((t & 63) == 0) zred[t >> 6] = z;
    }
    __syncthreads();

    // block-local ctx partial: P[d] = sum_s w_sh[s] * e[s0+s][d]  (L2-hot)
    {
        const float* eb = embeds + ((size_t)b * Ss + s0) * Dd + t * 4;
        f32x4 ca = (f32x4){0.f, 0.f, 0.f, 0.f};
        #pragma unroll 8
        for (int s = 0; s < 128; s++) {
            const float wgt = w_sh[s];
            const f32x4 ev = *(const f32x4*)(eb + (size_t)s * Dd);
            ca[0] = fmaf(wgt, ev[0], ca[0]);
            ca[1] = fmaf(wgt, ev[1], ca[1]);
            ca[2] = fmaf(wgt, ev[2], ca[2]);
            ca[3] = fmaf(wgt, ev[3], ca[3]);
        }
        *(f32x4*)(partial + ((size_t)(b * NBLK + blk)) * Dd + t * 4) = ca;
        if (t == 0) {
            mblk[b * NBLK + blk] = Mb;
            zblk[b * NBLK + blk] = zred[0] + zred[1];
        }
    }
}

// ------- Pass 2: global flash combine + tok_diag (parallel over d) -------
__global__ __launch_bounds__(256) void k_finish(
    const float* __restrict__ mblk, const float* __restrict__ zblk,
    const float* __restrict__ partial, const float* __restrict__ tok_diag,
    float* __restrict__ out)
{
    __shared__ float cf[NBLK];
    const int b  = blockIdx.x >> 2;      // batch
    const int dq = blockIdx.x & 3;       // d quarter (256 floats)
    const int t  = threadIdx.x;

    if (t < 64) {
        const float mv = (t < NBLK) ? mblk[b * NBLK + t] : -3.4e38f;
        float M = mv;
        #pragma unroll
        for (int o = 32; o >= 1; o >>= 1) M = fmaxf(M, __shfl_xor(M, o));
        const float zv = (t < NBLK) ? zblk[b * NBLK + t] * expf(mv - M) : 0.f;
        float Z = zv;
        #pragma unroll
        for (int o = 32; o >= 1; o >>= 1) Z += __shfl_xor(Z, o);
        if (t < NBLK) cf[t] = expf(mv - M) / Z;
    }
    __syncthreads();

    const int d = dq * 256 + t;          // one float per thread, coalesced
    float a = 0.f;
    #pragma unroll
    for (int j = 0; j < NBLK; j++)
        a = fmaf(cf[j], partial[((size_t)(b * NBLK + j)) * Dd + d], a);
    out[(size_t)b * Dd + d] = a * tok_diag[d];
}

extern "C" void kernel_launch(void* const* d_in, const int* in_sizes, int n_in,
                              void* d_out, int out_size, void* d_ws, size_t ws_size,
                              hipStream_t stream) {
    const float* embeds    = (const float*)d_in[0];
    const float* mask      = (const float*)d_in[1];
    const float* latent    = (const float*)d_in[2];
    const float* att_diag  = (const float*)d_in[3];
    const float* tok_diag  = (const float*)d_in[4];
    const float* pos_table = (const float*)d_in[5];
    const float* tok_mult  = (const float*)d_in[6];
    const int*   rel_ids   = (const int*)d_in[7];
    float* out = (float*)d_out;

    char* ws = (char*)d_ws;
    _Float16* whi    = (_Float16*)(ws);              // 512 KB
    float*    partial= (float*)(ws + 524288);        // 2 MB
    float*    mblk   = (float*)(ws + 2621440);       // 2 KB
    float*    zblk   = (float*)(ws + 2623488);       // 2 KB

    k_prep_w<<<(Cc * Dd) / 256, 256, 0, stream>>>(latent, att_diag, whi);
    k_scores_mfma<<<Bb * NBLK, 256, 0, stream>>>(
        embeds, mask, pos_table, tok_mult, rel_ids, whi, partial, mblk, zblk);
    k_finish<<<Bb * 4, 256, 0, stream>>>(mblk, zblk, partial, tok_diag, out);
}

// Round 20
// 113.633 us; speedup vs baseline: 1.7287x; 1.0680x over previous
//
#include <hip/hip_runtime.h>
#include <hip/hip_bf16.h>

// B=32, S=2048, D=1024, C=256
//   top[b,s] = max_c sum_d (latent[c,d]*att_diag[d]) * (tm*embeds[b,s,d] + pos_table[rel+64,d])
//   p = softmax_s(top*m + (m-1)*NEG);  ctx[b,d] = tok_diag[d] * sum_s embeds*p
//
// R20 = R19 + "stage everything": the e-tile (128 tok x 32 k, 16KB f32) is
// now ALSO staged via global_load_lds (dbuf), with both-sides XOR swizzle
// (linear LDS dst, pre-swizzled global src u^=(row&7), swizzled ds_read) so
// the 16-lane same-column read is 2-way (free). Waves carry NO VMEM->reg
// dependency except the L1-hot pos gather (4 loads, prefetched 1 kc ahead).
// Per-iter VMEM queue: [8 DMA, 4 p]; vmcnt(4) drains exactly the DMA.
// 2-term split-fp16 MFMA (W_hi*(x_hi+x_lo), x = tm*e + p); flash epilogue;
// parallel k_finish (128 blocks).
//
// ws: whi 512K | partial 2M | mblk 2K | zblk 2K

#define HC 64
#define NEGV 1000000000000.0f

constexpr int Bb = 32, Ss = 2048, Dd = 1024, Cc = 256;
constexpr int NKC = 32;                 // k-chunks of 32
constexpr int CT = Cc / 16;             // 16 c-tiles
constexpr int NBLK = 16;                // 128-token blocks per batch

typedef _Float16 f16x8 __attribute__((ext_vector_type(8)));
typedef float    f32x4 __attribute__((ext_vector_type(4)));

// ---------------- Pass 0: W_hi -> per-kc fragment chunks ----------
// layout: whi[kc][ct][lane][8] (16KB/kc)
// A-frag map: lane = (c%16) + 16*g holds A[c][k = kc*32 + 8g + i]
__global__ __launch_bounds__(256) void k_prep_w(
    const float* __restrict__ latent, const float* __restrict__ att_diag,
    _Float16* __restrict__ whi)
{
    const int idx = blockIdx.x * 256 + threadIdx.x;   // c*Dd + k
    const int c = idx >> 10, k = idx & 1023;
    const float wv = latent[idx] * att_diag[k];
    const int kc = k >> 5, g = (k >> 3) & 3, i = k & 7;
    const int lane = (c & 15) + 16 * g, ct = c >> 4;
    whi[(size_t)kc * 8192 + (size_t)ct * 512 + lane * 8 + i] = (_Float16)wv;
}

// ------- Pass 1: scores via MFMA, block max/sumexp, flash ctx partial -----
__global__ __launch_bounds__(256, 2) void k_scores_mfma(
    const float* __restrict__ embeds,    // [B][S][D]
    const float* __restrict__ mask,      // [B][S]
    const float* __restrict__ pos_table, // [132][D]
    const float* __restrict__ tok_mult,  // [1]
    const int*   __restrict__ rel_ids,   // [B][S]
    const _Float16* __restrict__ whi,    // [NKC][CT][64][8]
    float* __restrict__ partial,         // [B][NBLK][D]
    float* __restrict__ mblk,            // [B][NBLK]
    float* __restrict__ zblk)            // [B][NBLK]
{
    __shared__ _Float16 sbufW[2][8192];  // 2 x 16KB (W_hi chunks)
    __shared__ float    sbufE[2][4096];  // 2 x 16KB (e tiles, swizzled)
    __shared__ float l_sh[128];
    __shared__ float w_sh[128];
    __shared__ float red2[2], zred[2];

    const int t  = threadIdx.x;
    const int wv = t >> 6;      // wave 0..3
    const int l  = t & 63;
    const int lr = l & 15;      // token within set / output col
    const int lg = l >> 4;      // k-group

    const int b   = blockIdx.x >> 4;     // 16 blocks of 128 tokens per batch
    const int blk = blockIdx.x & 15;
    const int s0  = blk * 128;

    const float tm = tok_mult[0];

    const float* prow[2];
    #pragma unroll
    for (int st = 0; st < 2; st++) {
        const int tok = s0 + wv * 32 + st * 16 + lr;
        prow[st] = pos_table + (size_t)(rel_ids[b * Ss + tok] + HC) * Dd;
    }

    f32x4 acc[CT][2];
    #pragma unroll
    for (int ct = 0; ct < CT; ct++)
        #pragma unroll
        for (int st = 0; st < 2; st++) acc[ct][st] = (f32x4){0.f, 0.f, 0.f, 0.f};

    // pos prefetch registers (one kc ahead): 4 gather loads (L1-hot rows)
    f32x4 p0[2], p1[2];
    auto loadP = [&](int kc) {
        const int k0 = kc * 32 + lg * 8;
        #pragma unroll
        for (int st = 0; st < 2; st++) {
            p0[st] = *(const f32x4*)(prow[st] + k0);
            p1[st] = *(const f32x4*)(prow[st] + k0 + 4);
        }
    };

    // stage one 16KB W_hi chunk: 16 wave-chunks of 1KB (4 insts/thread)
    auto stageW = [&](int kc, _Float16* dst) {
        const _Float16* src = whi + (size_t)kc * 8192;
        #pragma unroll
        for (int i = 0; i < 4; i++) {
            const int off = (i * 4 + wv) << 9;   // elems; 1KB chunks
            __builtin_amdgcn_global_load_lds(
                (const __attribute__((address_space(1))) void*)(src + off + l * 8),
                (__attribute__((address_space(3))) void*)(dst + off),
                16, 0, 0);
        }
    };

    // stage one 16KB e tile [128 rows][8 16B-units], XOR-swizzled:
    // LDS unit j = row*8 + u holds e[row][u ^ (row&7)] (16B units).
    // Per-lane global src is pre-swizzled; LDS dst is linear (wave base).
    auto stageE = [&](int kc, float* dst) {
        const float* ebase = embeds + ((size_t)b * Ss + s0) * Dd + kc * 32;
        #pragma unroll
        for (int i = 0; i < 4; i++) {
            const int jbase = i * 256 + wv * 64;     // unit idx of lane 0
            const int j = jbase + l;                 // this lane's unit
            const int row = j >> 3, u = j & 7;
            const float* src = ebase + (size_t)row * Dd + ((u ^ (row & 7)) << 2);
            __builtin_amdgcn_global_load_lds(
                (const __attribute__((address_space(1))) void*)src,
                (__attribute__((address_space(3))) void*)(dst + jbase * 4),
                16, 0, 0);
        }
    };

    // prologue: DMA both tiles (oldest 8), then pos
    stageW(0, sbufW[0]);
    stageE(0, sbufE[0]);
    loadP(0);
    asm volatile("s_waitcnt vmcnt(4)" ::: "memory");  // 8 DMA drained; p in flight
    __builtin_amdgcn_s_barrier();

    int cur = 0;
    for (int kc = 0; kc < NKC; kc++) {
        if (kc + 1 < NKC) {
            stageW(kc + 1, sbufW[cur ^ 1]);   // 4 DMA
            stageE(kc + 1, sbufE[cur ^ 1]);   // 4 DMA
        }

        // build B frags: e from swizzled LDS, pos from prefetch regs
        f16x8 bh[2], bl[2];
        {
            const float* es = sbufE[cur];
            #pragma unroll
            for (int st = 0; st < 2; st++) {
                const int row = wv * 32 + st * 16 + lr;
                const int sw  = row & 7;
                const f32x4 x0 = *(const f32x4*)(es + row * 32 + (((lg << 1)    ) ^ sw) * 4);
                const f32x4 x1 = *(const f32x4*)(es + row * 32 + (((lg << 1) | 1) ^ sw) * 4);
                float e[8], p[8];
                *(f32x4*)&e[0] = x0;     *(f32x4*)&e[4] = x1;
                *(f32x4*)&p[0] = p0[st]; *(f32x4*)&p[4] = p1[st];
                #pragma unroll
                for (int i = 0; i < 8; i++) {
                    const float x = fmaf(tm, e[i], p[i]);
                    const _Float16 h = (_Float16)x;
                    bh[st][i] = h;
                    bl[st][i] = (_Float16)(x - (float)h);
                }
            }
        }
        if (kc + 1 < NKC) loadP(kc + 1);   // 4 gather loads; stay in flight

        const _Float16* base = sbufW[cur];
        #pragma unroll
        for (int ct = 0; ct < CT; ct++) {
            const f16x8 ah = *(const f16x8*)(base + ct * 512 + l * 8);
            #pragma unroll
            for (int st = 0; st < 2; st++) {
                acc[ct][st] = __builtin_amdgcn_mfma_f32_16x16x32_f16(ah, bh[st], acc[ct][st], 0, 0, 0);
                acc[ct][st] = __builtin_amdgcn_mfma_f32_16x16x32_f16(ah, bl[st], acc[ct][st], 0, 0, 0);
            }
        }
        // drain exactly this iter's 8 DMA (oldest); p(kc+1) stays in flight
        if (kc + 1 < NKC) { asm volatile("s_waitcnt vmcnt(4)" ::: "memory"); }
        else              { asm volatile("s_waitcnt vmcnt(0)" ::: "memory"); }
        __builtin_amdgcn_s_barrier();
        cur ^= 1;
    }

    // masked logit per token -> LDS
    #pragma unroll
    for (int st = 0; st < 2; st++) {
        float mx = acc[0][st][0];
        #pragma unroll
        for (int ct = 0; ct < CT; ct++)
            #pragma unroll
            for (int r = 0; r < 4; r++) mx = fmaxf(mx, acc[ct][st][r]);
        mx = fmaxf(mx, __shfl_xor(mx, 16));
        mx = fmaxf(mx, __shfl_xor(mx, 32));
        if (lg == 0) {
            const int si = wv * 32 + st * 16 + lr;   // token within block
            const int s  = s0 + si;
            const float mk = mask[b * Ss + s];
            l_sh[si] = mx * mk + (mk - 1.0f) * NEGV;
        }
    }
    __syncthreads();

    // block max M_b over the 128 logits
    if (t < 128) {
        float v = l_sh[t];
        #pragma unroll
        for (int o = 32; o >= 1; o >>= 1) v = fmaxf(v, __shfl_xor(v, o));
        if ((t & 63) == 0) red2[t >> 6] = v;
    }
    __syncthreads();
    const float Mb = fmaxf(red2[0], red2[1]);
    if (t < 128) w_sh[t] = expf(l_sh[t] - Mb);
    __syncthreads();
    if (t < 128) {
        float z = w_sh[t];
        #pragma unroll
        for (int o = 32; o >= 1; o >>= 1) z += __shfl_xor(z, o);
        if ((t & 63) == 0) zred[t >> 6] = z;
    }
    __syncthreads();

    // block-local ctx partial: P[d] = sum_s w_sh[s] * e[s0+s][d]  (L2-hot)
    {
        const float* eb = embeds + ((size_t)b * Ss + s0) * Dd + t * 4;
        f32x4 ca = (f32x4){0.f, 0.f, 0.f, 0.f};
        #pragma unroll 8
        for (int s = 0; s < 128; s++) {
            const float wgt = w_sh[s];
            const f32x4 ev = *(const f32x4*)(eb + (size_t)s * Dd);
            ca[0] = fmaf(wgt, ev[0], ca[0]);
            ca[1] = fmaf(wgt, ev[1], ca[1]);
            ca[2] = fmaf(wgt, ev[2], ca[2]);
            ca[3] = fmaf(wgt, ev[3], ca[3]);
        }
        *(f32x4*)(partial + ((size_t)(b * NBLK + blk)) * Dd + t * 4) = ca;
        if (t == 0) {
            mblk[b * NBLK + blk] = Mb;
            zblk[b * NBLK + blk] = zred[0] + zred[1];
        }
    }
}

// ------- Pass 2: global flash combine + tok_diag (parallel over d) -------
__global__ __launch_bounds__(256) void k_finish(
    const float* __restrict__ mblk, const float* __restrict__ zblk,
    const float* __restrict__ partial, const float* __restrict__ tok_diag,
    float* __restrict__ out)
{
    __shared__ float cf[NBLK];
    const int b  = blockIdx.x >> 2;      // batch
    const int dq = blockIdx.x & 3;       // d quarter (256 floats)
    const int t  = threadIdx.x;

    if (t < 64) {
        const float mv = (t < NBLK) ? mblk[b * NBLK + t] : -3.4e38f;
        float M = mv;
        #pragma unroll
        for (int o = 32; o >= 1; o >>= 1) M = fmaxf(M, __shfl_xor(M, o));
        const float zv = (t < NBLK) ? zblk[b * NBLK + t] * expf(mv - M) : 0.f;
        float Z = zv;
        #pragma unroll
        for (int o = 32; o >= 1; o >>= 1) Z += __shfl_xor(Z, o);
        if (t < NBLK) cf[t] = expf(mv - M) / Z;
    }
    __syncthreads();

    const int d = dq * 256 + t;          // one float per thread, coalesced
    float a = 0.f;
    #pragma unroll
    for (int j = 0; j < NBLK; j++)
        a = fmaf(cf[j], partial[((size_t)(b * NBLK + j)) * Dd + d], a);
    out[(size_t)b * Dd + d] = a * tok_diag[d];
}

extern "C" void kernel_launch(void* const* d_in, const int* in_sizes, int n_in,
                              void* d_out, int out_size, void* d_ws, size_t ws_size,
                              hipStream_t stream) {
    const float* embeds    = (const float*)d_in[0];
    const float* mask      = (const float*)d_in[1];
    const float* latent    = (const float*)d_in[2];
    const float* att_diag  = (const float*)d_in[3];
    const float* tok_diag  = (const float*)d_in[4];
    const float* pos_table = (const float*)d_in[5];
    const float* tok_mult  = (const float*)d_in[6];
    const int*   rel_ids   = (const int*)d_in[7];
    float* out = (float*)d_out;

    char* ws = (char*)d_ws;
    _Float16* whi    = (_Float16*)(ws);              // 512 KB
    float*    partial= (float*)(ws + 524288);        // 2 MB
    float*    mblk   = (float*)(ws + 2621440);       // 2 KB
    float*    zblk   = (float*)(ws + 2623488);       // 2 KB

    k_prep_w<<<(Cc * Dd) / 256, 256, 0, stream>>>(latent, att_diag, whi);
    k_scores_mfma<<<Bb * NBLK, 256, 0, stream>>>(
        embeds, mask, pos_table, tok_mult, rel_ids, whi, partial, mblk, zblk);
    k_finish<<<Bb * 4, 256, 0, stream>>>(mblk, zblk, partial, tok_diag, out);
}